// Round 4
// baseline (108.431 us; speedup 1.0000x reference)
//
#include <hip/hip_runtime.h>
#include <math.h>

// SoAGREE fused forward. One block (256 thr = 4 waves) per batch element.
// B=1024, M=16, F=32, D=64, fp32.
// Phase 1: wave w processes member PAIRS (w*4+2pr, w*4+2pr+1), pr=0,1.
//   lane = (f = lane&31, mh = lane>>5): member m = pairbase + mh, row f.
//   Each lane gathers its FULL 256B follow row into 16 float4 regs.
//   Score MLP: d wave-uniform -> fatt_w1 streams in as SGPR (s_load) operands.
//   Weighted sum: register butterfly over the 32 f-lanes (__shfl_xor,
//   masks 16..1, keep-half select) -> lane f ends with d={2f,2f+1} sums.
//   NO LDS transpose tile, NO intra-loop fences -> ~10.5 KB LDS, 4 blocks/CU.

__global__ __launch_bounds__(256, 4) void soagree_kernel(
    const int* __restrict__ group_inputs,   // [B]
    const int* __restrict__ item_inputs,    // [B]
    const int* __restrict__ member_ids,     // [B,16]
    const int* __restrict__ follow_ids,     // [B,16,32]
    const float* __restrict__ user_table,   // [NU,64]
    const float* __restrict__ item_table,   // [NI,64]
    const float* __restrict__ group_table,  // [NG,64]
    const float* __restrict__ follow_table, // [NU,64]
    const float* __restrict__ fatt_w1, const float* __restrict__ fatt_b1,
    const float* __restrict__ fatt_w2, const float* __restrict__ fatt_b2,
    const float* __restrict__ att_w1,  const float* __restrict__ att_b1,
    const float* __restrict__ att_w2,  const float* __restrict__ att_b2,
    const float* __restrict__ pred_w1, const float* __restrict__ pred_b1,
    const float* __restrict__ pred_w2, const float* __restrict__ pred_b2,
    float* __restrict__ out)               // [B]
{
    const int b    = blockIdx.x;
    const int tid  = threadIdx.x;
    const int w    = tid >> 6;    // wave id 0..3
    const int lane = tid & 63;
    const int f    = lane & 31;   // follow row
    const int mh   = lane >> 5;   // which member of the pair

    __shared__ float s_uemb[16][66];      // member user embeddings (stride 66: 8B-aligned float2 cols)
    __shared__ float s_mem[16][66];       // aggregated member vectors
    __shared__ float s_upart[16][16];     // u @ fatt_w1[64:] + fatt_b1
    __shared__ float s_ipart[16];         // i @ att_w1[64:] + att_b1
    __shared__ float s_iemb[64];
    __shared__ float s_gemb[64];
    __shared__ float s_gfin[64];
    __shared__ float s_scores[16];
    __shared__ float s_mw[16];

    // ---- phase 0: stage embeddings ----
    if (tid < 64) {
        s_iemb[tid] = item_table[(size_t)item_inputs[b] * 64 + tid];
    } else if (tid < 128) {
        s_gemb[tid - 64] = group_table[(size_t)group_inputs[b] * 64 + (tid - 64)];
    }
    for (int m = w; m < 16; m += 4) {
        int uid = member_ids[b * 16 + m];
        s_uemb[m][lane] = user_table[(size_t)uid * 64 + lane];
    }
    __syncthreads();

    // ---- phase 0.5: u_part[m][j], i_part[j] (w1 hi-halves from global, L1-hot) ----
    {
        int m = tid >> 4, j = tid & 15;
        float acc = fatt_b1[j];
        #pragma unroll
        for (int d = 0; d < 64; ++d)
            acc += s_uemb[m][d] * fatt_w1[(64 + d) * 16 + j];
        s_upart[m][j] = acc;
    }
    if (tid < 16) {
        float a2 = att_b1[tid];
        #pragma unroll
        for (int d = 0; d < 64; ++d)
            a2 += s_iemb[d] * att_w1[(64 + d) * 16 + tid];
        s_ipart[tid] = a2;
    }
    __syncthreads();

    // ---- phase 1: follow attention, 2 member-pairs per wave, register-only ----
    #pragma unroll
    for (int pr = 0; pr < 2; ++pr) {
        const int pb = w * 4 + pr * 2;   // pair's first member
        const int m  = pb + mh;          // this lane's member

        // gather: one coalesced id load, then full 256B row -> 16 float4 regs
        const int fid = follow_ids[b * 512 + pb * 32 + lane];
        const float4* src = (const float4*)(follow_table + (size_t)fid * 64);
        float4 r4[16];
        #pragma unroll
        for (int q = 0; q < 16; ++q) r4[q] = src[q];
        float* rf = (float*)r4;          // all indices below are compile-time

        // hacc init from s_upart (broadcast b128 reads)
        float hacc[16];
        #pragma unroll
        for (int jj = 0; jj < 4; ++jj) {
            float4 up = *(const float4*)&s_upart[m][jj * 4];
            hacc[jj * 4 + 0] = up.x; hacc[jj * 4 + 1] = up.y;
            hacc[jj * 4 + 2] = up.z; hacc[jj * 4 + 3] = up.w;
        }

        // score MLP: d wave-uniform -> fatt_w1[d*16+j] is an SGPR operand
        #pragma unroll
        for (int d = 0; d < 64; ++d) {
            const float v = rf[d];
            #pragma unroll
            for (int j = 0; j < 16; ++j)
                hacc[j] += v * fatt_w1[d * 16 + j];
        }
        float sc = fatt_b2[0];
        #pragma unroll
        for (int j = 0; j < 16; ++j)
            sc += fmaxf(hacc[j], 0.f) * fatt_w2[j];

        // softmax over the 32 f-lanes of this half (masks <32 stay in-half)
        float mx = sc;
        #pragma unroll
        for (int mk = 16; mk >= 1; mk >>= 1) mx = fmaxf(mx, __shfl_xor(mx, mk));
        const float e = __expf(sc - mx);
        float se = e;
        #pragma unroll
        for (int mk = 16; mk >= 1; mk >>= 1) se += __shfl_xor(se, mk);
        const float fwv = e / se;

        // pre-scale the row by its softmax weight
        #pragma unroll
        for (int d = 0; d < 64; ++d) rf[d] *= fwv;

        // register butterfly over the 32 f-lanes: each step halves rows & d-range.
        // After 5 steps lane f holds column sums for d = 2f, 2f+1.
        #define BSTEP(M, S)                                                  \
        {                                                                    \
            const bool hi = (lane & (M)) != 0;                               \
            _Pragma("unroll")                                                \
            for (int k = 0; k < (S) / 2; ++k) {                              \
                float send = hi ? rf[k] : rf[k + (S) / 2];                   \
                float recv = __shfl_xor(send, (M));                          \
                float keep = hi ? rf[k + (S) / 2] : rf[k];                   \
                rf[k] = keep + recv;                                         \
            }                                                                \
        }
        BSTEP(16, 64)
        BSTEP(8, 32)
        BSTEP(4, 16)
        BSTEP(2, 8)
        BSTEP(1, 4)
        #undef BSTEP

        // members[m][2f..2f+1] = column sums + u_emb
        float2 ue = *(const float2*)&s_uemb[m][2 * f];
        float2 res; res.x = rf[0] + ue.x; res.y = rf[1] + ue.y;
        *(float2*)&s_mem[m][2 * f] = res;
    }
    __syncthreads();

    // ---- phase 2: member attention (att_w1 lo-half from global, L1-hot) ----
    {
        int m = tid >> 4, j = tid & 15;
        float acc = s_ipart[j];
        #pragma unroll
        for (int d = 0; d < 64; ++d)
            acc += s_mem[m][d] * att_w1[d * 16 + j];
        float contrib = fmaxf(acc, 0.f) * att_w2[j];
        #pragma unroll
        for (int mk = 8; mk >= 1; mk >>= 1) contrib += __shfl_xor(contrib, mk);
        if (j == 0) s_scores[m] = contrib + att_b2[0];
    }
    __syncthreads();
    if (tid < 16) {
        float s = s_scores[tid];
        float mx2 = s;
        #pragma unroll
        for (int mk = 8; mk >= 1; mk >>= 1) mx2 = fmaxf(mx2, __shfl_xor(mx2, mk));
        float e2 = __expf(s - mx2);
        float sm2 = e2;
        #pragma unroll
        for (int mk = 8; mk >= 1; mk >>= 1) sm2 += __shfl_xor(sm2, mk);
        s_mw[tid] = e2 / sm2;
    }
    __syncthreads();
    if (tid < 64) {
        float g = s_gemb[tid];
        #pragma unroll
        for (int mm = 0; mm < 16; ++mm)
            g += s_mw[mm] * s_mem[mm][tid];
        s_gfin[tid] = g;
    }
    __syncthreads();

    // ---- phase 3: NCF predict head ----
    if (tid < 8) {
        const int j = tid;
        float acc = pred_b1[j];
        #pragma unroll 16
        for (int k = 0; k < 64; ++k) {
            float g = s_gfin[k], ie = s_iemb[k];
            acc += (g * ie) * pred_w1[k * 8 + j];
            acc += g  * pred_w1[(64 + k) * 8 + j];
            acc += ie * pred_w1[(128 + k) * 8 + j];
        }
        float contrib = fmaxf(acc, 0.f) * pred_w2[j];
        #pragma unroll
        for (int mk = 4; mk >= 1; mk >>= 1) contrib += __shfl_xor(contrib, mk);
        if (j == 0) {
            float z = contrib + pred_b2[0];
            out[b] = 1.f / (1.f + __expf(-z));
        }
    }
}

extern "C" void kernel_launch(void* const* d_in, const int* in_sizes, int n_in,
                              void* d_out, int out_size, void* d_ws, size_t ws_size,
                              hipStream_t stream) {
    const int*   group_inputs = (const int*)d_in[0];
    const int*   item_inputs  = (const int*)d_in[1];
    const int*   member_ids   = (const int*)d_in[2];
    const int*   follow_ids   = (const int*)d_in[3];
    const float* user_table   = (const float*)d_in[4];
    const float* item_table   = (const float*)d_in[5];
    const float* group_table  = (const float*)d_in[6];
    const float* follow_table = (const float*)d_in[7];
    const float* fatt_w1 = (const float*)d_in[8];
    const float* fatt_b1 = (const float*)d_in[9];
    const float* fatt_w2 = (const float*)d_in[10];
    const float* fatt_b2 = (const float*)d_in[11];
    const float* att_w1  = (const float*)d_in[12];
    const float* att_b1  = (const float*)d_in[13];
    const float* att_w2  = (const float*)d_in[14];
    const float* att_b2  = (const float*)d_in[15];
    const float* pred_w1 = (const float*)d_in[16];
    const float* pred_b1 = (const float*)d_in[17];
    const float* pred_w2 = (const float*)d_in[18];
    const float* pred_b2 = (const float*)d_in[19];
    float* outp = (float*)d_out;

    const int B = in_sizes[0];   // 1024

    soagree_kernel<<<B, 256, 0, stream>>>(
        group_inputs, item_inputs, member_ids, follow_ids,
        user_table, item_table, group_table, follow_table,
        fatt_w1, fatt_b1, fatt_w2, fatt_b2,
        att_w1, att_b1, att_w2, att_b2,
        pred_w1, pred_b1, pred_w2, pred_b2,
        outp);
}

// Round 5
// 56.047 us; speedup vs baseline: 1.9346x; 1.9346x over previous
//
#include <hip/hip_runtime.h>
#include <math.h>

// SoAGREE fused forward. One block (256 thr = 4 waves) per batch element.
// B=1024, M=16, F=32, D=64, fp32.
// Wave w owns members 4w..4w+3, processed as two pairs (pr=0,1).
// Per pair: 64 follow rows staged global->LDS via global_load_lds (16B,
// line-coalesced, XOR-preswizzled source so row read-back is conflict-min),
// then lane (f = lane&31, mh = lane>>5) reads its FULL row (16 ds_read_b128)
// into regs, runs the score MLP with SGPR-streamed fatt_w1, softmax over the
// 32 f-lanes, scales the row, and reduces columns with a register butterfly.
// Phase 1 is barrier-free; STAGE(pair1) flies under pair0's MLP.

__global__ __launch_bounds__(256) void soagree_kernel(
    const int* __restrict__ group_inputs,   // [B]
    const int* __restrict__ item_inputs,    // [B]
    const int* __restrict__ member_ids,     // [B,16]
    const int* __restrict__ follow_ids,     // [B,16,32]
    const float* __restrict__ user_table,   // [NU,64]
    const float* __restrict__ item_table,   // [NI,64]
    const float* __restrict__ group_table,  // [NG,64]
    const float* __restrict__ follow_table, // [NU,64]
    const float* __restrict__ fatt_w1, const float* __restrict__ fatt_b1,
    const float* __restrict__ fatt_w2, const float* __restrict__ fatt_b2,
    const float* __restrict__ att_w1,  const float* __restrict__ att_b1,
    const float* __restrict__ att_w2,  const float* __restrict__ att_b2,
    const float* __restrict__ pred_w1, const float* __restrict__ pred_b1,
    const float* __restrict__ pred_w2, const float* __restrict__ pred_b2,
    float* __restrict__ out)               // [B]
{
    const int b    = blockIdx.x;
    const int tid  = threadIdx.x;
    const int w    = tid >> 6;    // wave id 0..3
    const int lane = tid & 63;
    const int f    = lane & 31;   // follow row within member
    const int mh   = lane >> 5;   // which member of the pair

    __shared__ float s_tile[4][4096];     // per-wave pair tile: 64 rows x 64 f
    __shared__ int   s_ids[4][128];       // per-wave follow ids (4 members)
    __shared__ float s_uemb[16][66];      // member user embeddings
    __shared__ float s_mem[16][66];       // aggregated member vectors
    __shared__ float s_upart[16][16];     // u @ fatt_w1[64:] + fatt_b1
    __shared__ float s_ipart[16];         // i @ att_w1[64:] + att_b1
    __shared__ float s_iemb[64];
    __shared__ float s_gemb[64];
    __shared__ float s_gfin[64];
    __shared__ float s_scores[16];
    __shared__ float s_mw[16];

    float* const tile = s_tile[w];

    // ---- phase 0 (wave-local): ids, own uemb, (wave0/1: iemb/gemb) ----
    if (tid < 64) {
        s_iemb[tid] = item_table[(size_t)item_inputs[b] * 64 + tid];
    } else if (tid < 128) {
        s_gemb[tid - 64] = group_table[(size_t)group_inputs[b] * 64 + (tid - 64)];
    }
    s_ids[w][lane]      = follow_ids[b * 512 + 128 * w + lane];
    s_ids[w][lane + 64] = follow_ids[b * 512 + 128 * w + lane + 64];
    #pragma unroll
    for (int it = 0; it < 4; ++it) {
        const int m   = w * 4 + it;
        const int uid = member_ids[b * 16 + m];          // wave-uniform -> s_load
        s_uemb[m][lane] = user_table[(size_t)uid * 64 + lane];
    }

    // STAGE: issue 16 global_load_lds (16B) for pair pr into this wave's tile.
    // Physical slot (row r, s) holds logical float4 (s ^ (r&7)) of row r.
    #define STAGE(pr)                                                          \
    {                                                                          \
        _Pragma("unroll")                                                      \
        for (int g = 0; g < 16; ++g) {                                         \
            const int r   = 4 * g + (lane >> 4);                               \
            const int fid = s_ids[w][(pr) * 64 + r];                           \
            const int swz = (lane & 15) ^ (r & 7);                             \
            const float* gp = follow_table + (size_t)fid * 64 + (swz << 2);    \
            __builtin_amdgcn_global_load_lds(                                  \
                (const __attribute__((address_space(1))) void*)gp,             \
                (__attribute__((address_space(3))) void*)(tile + g * 256),     \
                16, 0, 0);                                                     \
        }                                                                      \
    }

    STAGE(0)   // pair0 latency hides under phase 0.5

    // ---- phase 0.5 (wave-local): u_part for own members; wave0: i_part ----
    {
        int m = tid >> 4, j = tid & 15;      // wave w handles m = 4w..4w+3
        float acc = fatt_b1[j];
        #pragma unroll
        for (int d = 0; d < 64; ++d)
            acc += s_uemb[m][d] * fatt_w1[(64 + d) * 16 + j];
        s_upart[m][j] = acc;
    }
    if (tid < 16) {
        float a2 = att_b1[tid];
        #pragma unroll
        for (int d = 0; d < 64; ++d)
            a2 += s_iemb[d] * att_w1[(64 + d) * 16 + tid];
        s_ipart[tid] = a2;
    }

    const float fb2 = fatt_b2[0];
    const int   rrow = (mh << 5) | f;    // this lane's row in the pair tile
    const int   sw   = f & 7;            // read-back XOR

    // ---- phase 1: two pairs, barrier-free, software-pipelined ----
    #pragma unroll
    for (int pr = 0; pr < 2; ++pr) {
        const int pb = w * 4 + pr * 2;   // pair's first member
        const int m  = pb + mh;          // this lane's member

        // wait: this pair's tile is fully in LDS
        asm volatile("s_waitcnt vmcnt(0)" ::: "memory");
        __builtin_amdgcn_sched_barrier(0);

        // read my row into regs (16 x ds_read_b128, conflict-minimal)
        float4 r4[16];
        #pragma unroll
        for (int q = 0; q < 16; ++q)
            r4[q] = *(const float4*)&tile[rrow * 64 + ((q ^ sw) << 2)];
        float* rf = (float*)r4;

        // tile is free once the reads retire -> launch next pair's DMA
        asm volatile("s_waitcnt lgkmcnt(0)" ::: "memory");
        __builtin_amdgcn_sched_barrier(0);
        if (pr == 0) STAGE(1)

        // hacc init from s_upart
        float hacc[16];
        #pragma unroll
        for (int jj = 0; jj < 4; ++jj) {
            float4 up = *(const float4*)&s_upart[m][jj * 4];
            hacc[jj * 4 + 0] = up.x; hacc[jj * 4 + 1] = up.y;
            hacc[jj * 4 + 2] = up.z; hacc[jj * 4 + 3] = up.w;
        }

        // score MLP: d wave-uniform -> fatt_w1[d*16+j] streams as SGPR
        #pragma unroll
        for (int d = 0; d < 64; ++d) {
            const float v = rf[d];
            #pragma unroll
            for (int j = 0; j < 16; ++j)
                hacc[j] += v * fatt_w1[d * 16 + j];
        }
        float sc = fb2;
        #pragma unroll
        for (int j = 0; j < 16; ++j)
            sc += fmaxf(hacc[j], 0.f) * fatt_w2[j];

        // softmax over the 32 f-lanes of this half
        float mx = sc;
        #pragma unroll
        for (int mk = 16; mk >= 1; mk >>= 1) mx = fmaxf(mx, __shfl_xor(mx, mk));
        const float e = __expf(sc - mx);
        float se = e;
        #pragma unroll
        for (int mk = 16; mk >= 1; mk >>= 1) se += __shfl_xor(se, mk);
        const float fwv = e / se;

        // pre-scale row, then register butterfly: after 5 steps lane f holds
        // column sums for d = 2f, 2f+1 of its member.
        #pragma unroll
        for (int d = 0; d < 64; ++d) rf[d] *= fwv;

        #define BSTEP(M, S)                                                  \
        {                                                                    \
            const bool hi = (lane & (M)) != 0;                               \
            _Pragma("unroll")                                                \
            for (int k = 0; k < (S) / 2; ++k) {                              \
                float send = hi ? rf[k] : rf[k + (S) / 2];                   \
                float recv = __shfl_xor(send, (M));                          \
                float keep = hi ? rf[k + (S) / 2] : rf[k];                   \
                rf[k] = keep + recv;                                         \
            }                                                                \
        }
        BSTEP(16, 64)
        BSTEP(8, 32)
        BSTEP(4, 16)
        BSTEP(2, 8)
        BSTEP(1, 4)
        #undef BSTEP

        float2 ue = *(const float2*)&s_uemb[m][2 * f];
        float2 res; res.x = rf[0] + ue.x; res.y = rf[1] + ue.y;
        *(float2*)&s_mem[m][2 * f] = res;
    }
    #undef STAGE
    __syncthreads();

    // ---- phase 2: member attention (att_w1 lo-half from global, L1-hot) ----
    {
        int m = tid >> 4, j = tid & 15;
        float acc = s_ipart[j];
        #pragma unroll
        for (int d = 0; d < 64; ++d)
            acc += s_mem[m][d] * att_w1[d * 16 + j];
        float contrib = fmaxf(acc, 0.f) * att_w2[j];
        #pragma unroll
        for (int mk = 8; mk >= 1; mk >>= 1) contrib += __shfl_xor(contrib, mk);
        if (j == 0) s_scores[m] = contrib + att_b2[0];
    }
    __syncthreads();
    if (tid < 16) {
        float s = s_scores[tid];
        float mx2 = s;
        #pragma unroll
        for (int mk = 8; mk >= 1; mk >>= 1) mx2 = fmaxf(mx2, __shfl_xor(mx2, mk));
        float e2 = __expf(s - mx2);
        float sm2 = e2;
        #pragma unroll
        for (int mk = 8; mk >= 1; mk >>= 1) sm2 += __shfl_xor(sm2, mk);
        s_mw[tid] = e2 / sm2;
    }
    __syncthreads();
    if (tid < 64) {
        float g = s_gemb[tid];
        #pragma unroll
        for (int mm = 0; mm < 16; ++mm)
            g += s_mw[mm] * s_mem[mm][tid];
        s_gfin[tid] = g;
    }
    __syncthreads();

    // ---- phase 3: NCF predict head ----
    if (tid < 8) {
        const int j = tid;
        float acc = pred_b1[j];
        #pragma unroll 16
        for (int k = 0; k < 64; ++k) {
            float g = s_gfin[k], ie = s_iemb[k];
            acc += (g * ie) * pred_w1[k * 8 + j];
            acc += g  * pred_w1[(64 + k) * 8 + j];
            acc += ie * pred_w1[(128 + k) * 8 + j];
        }
        float contrib = fmaxf(acc, 0.f) * pred_w2[j];
        #pragma unroll
        for (int mk = 4; mk >= 1; mk >>= 1) contrib += __shfl_xor(contrib, mk);
        if (j == 0) {
            float z = contrib + pred_b2[0];
            out[b] = 1.f / (1.f + __expf(-z));
        }
    }
}

extern "C" void kernel_launch(void* const* d_in, const int* in_sizes, int n_in,
                              void* d_out, int out_size, void* d_ws, size_t ws_size,
                              hipStream_t stream) {
    const int*   group_inputs = (const int*)d_in[0];
    const int*   item_inputs  = (const int*)d_in[1];
    const int*   member_ids   = (const int*)d_in[2];
    const int*   follow_ids   = (const int*)d_in[3];
    const float* user_table   = (const float*)d_in[4];
    const float* item_table   = (const float*)d_in[5];
    const float* group_table  = (const float*)d_in[6];
    const float* follow_table = (const float*)d_in[7];
    const float* fatt_w1 = (const float*)d_in[8];
    const float* fatt_b1 = (const float*)d_in[9];
    const float* fatt_w2 = (const float*)d_in[10];
    const float* fatt_b2 = (const float*)d_in[11];
    const float* att_w1  = (const float*)d_in[12];
    const float* att_b1  = (const float*)d_in[13];
    const float* att_w2  = (const float*)d_in[14];
    const float* att_b2  = (const float*)d_in[15];
    const float* pred_w1 = (const float*)d_in[16];
    const float* pred_b1 = (const float*)d_in[17];
    const float* pred_w2 = (const float*)d_in[18];
    const float* pred_b2 = (const float*)d_in[19];
    float* outp = (float*)d_out;

    const int B = in_sizes[0];   // 1024

    soagree_kernel<<<B, 256, 0, stream>>>(
        group_inputs, item_inputs, member_ids, follow_ids,
        user_table, item_table, group_table, follow_table,
        fatt_w1, fatt_b1, fatt_w2, fatt_b2,
        att_w1, att_b1, att_w2, att_b2,
        pred_w1, pred_b1, pred_w2, pred_b2,
        outp);
}